// Round 1
// baseline (537.865 us; speedup 1.0000x reference)
//
#include <hip/hip_runtime.h>
#include <hip/hip_bf16.h>

#define N_NODES 10000
#define N_EDGES 80000
#define FN 16
#define FE 8
#define HID 25
#define C1 32
#define C2 64

__device__ __forceinline__ float elu_f(float x) { return x > 0.f ? x : (expf(x) - 1.f); }

// --- K1: per-edge hidden layer for both convs: relu(ea@w1+b1), plus degree count ---
__global__ void k_edge_hidden(const float* __restrict__ ea, const int* __restrict__ ei,
                              const float* __restrict__ w1a, const float* __restrict__ b1a,
                              const float* __restrict__ w1b, const float* __restrict__ b1b,
                              float* __restrict__ hr1, float* __restrict__ hr2,
                              float* __restrict__ deg) {
    __shared__ float sw1a[FE * HID], sw1b[FE * HID], sb1a[HID], sb1b[HID];
    int tid = threadIdx.x;
    for (int i = tid; i < FE * HID; i += blockDim.x) { sw1a[i] = w1a[i]; sw1b[i] = w1b[i]; }
    if (tid < HID) { sb1a[tid] = b1a[tid]; sb1b[tid] = b1b[tid]; }
    __syncthreads();
    int e = blockIdx.x * blockDim.x + tid;
    if (e >= N_EDGES) return;
    float a[FE];
#pragma unroll
    for (int i = 0; i < FE; i++) a[i] = ea[e * FE + i];
#pragma unroll
    for (int k = 0; k < HID; k++) {
        float s1 = sb1a[k], s2 = sb1b[k];
#pragma unroll
        for (int i = 0; i < FE; i++) { s1 += a[i] * sw1a[i * HID + k]; s2 += a[i] * sw1b[i * HID + k]; }
        hr1[e * HID + k] = fmaxf(s1, 0.f);
        hr2[e * HID + k] = fmaxf(s2, 0.f);
    }
    atomicAdd(&deg[ei[N_EDGES + e]], 1.0f);
}

// --- K2: per-node precompute P[n,k,o] = sum_i x[n,i] * w2[k, i*COUT + o] ---
template <int CIN, int COUT>
__global__ void k_precompute_P(const float* __restrict__ xin, const float* __restrict__ w2,
                               float* __restrict__ P) {
    __shared__ float xn[CIN];
    int n = blockIdx.x;
    int tid = threadIdx.x;
    if (tid < CIN) xn[tid] = xin[n * CIN + tid];
    __syncthreads();
    for (int ko = tid; ko < HID * COUT; ko += blockDim.x) {
        int k = ko / COUT, o = ko % COUT;
        float s = 0.f;
#pragma unroll
        for (int i = 0; i < CIN; i++) s += xn[i] * w2[k * (CIN * COUT) + i * COUT + o];
        P[(size_t)n * (HID * COUT) + ko] = s;
    }
}

// --- K3: per-edge message msg[e,o] = sum_k hr[e,k]*P[src,k,o] + sum_i x[src,i]*b2[i,o];
//         atomic scatter into agg[dst,o] ---
template <int CIN, int COUT>
__global__ void k_edge_msg(const float* __restrict__ xin, const int* __restrict__ ei,
                           const float* __restrict__ hr, const float* __restrict__ P,
                           const float* __restrict__ b2, float* __restrict__ agg) {
    int t = blockIdx.x * blockDim.x + threadIdx.x;
    int e = t / COUT, o = t % COUT;
    if (e >= N_EDGES) return;
    int src = ei[e], dst = ei[N_EDGES + e];
    const float* Pr = P + (size_t)src * (HID * COUT) + o;
    const float* hre = hr + e * HID;
    float s = 0.f;
#pragma unroll
    for (int k = 0; k < HID; k++) s += hre[k] * Pr[k * COUT];
    const float* xr = xin + src * CIN;
#pragma unroll
    for (int i = 0; i < CIN; i++) s += xr[i] * b2[i * COUT + o];
    atomicAdd(&agg[dst * COUT + o], s);
}

// --- K4: node update: act = elu(x@root + agg/max(deg,1) + bias); accumulate BN sums ---
template <int CIN, int COUT>
__global__ void k_node_update(const float* __restrict__ xin, const float* __restrict__ root,
                              const float* __restrict__ bias, const float* __restrict__ agg,
                              const float* __restrict__ deg, float* __restrict__ act,
                              float* __restrict__ s1g, float* __restrict__ s2g) {
    __shared__ float l1[256], l2[256];
    int tid = threadIdx.x;
    int t = blockIdx.x * 256 + tid;
    int n = t / COUT, o = t % COUT;
    float a = 0.f;
    if (n < N_NODES) {
        float s = bias[o];
        const float* xr = xin + n * CIN;
#pragma unroll
        for (int i = 0; i < CIN; i++) s += xr[i] * root[i * COUT + o];
        s += agg[n * COUT + o] / fmaxf(deg[n], 1.0f);
        a = elu_f(s);
        act[n * COUT + o] = a;
    }
    l1[tid] = a; l2[tid] = a * a;
    __syncthreads();
    for (int s = 128; s >= COUT; s >>= 1) {
        if (tid < s) { l1[tid] += l1[tid + s]; l2[tid] += l2[tid + s]; }
        __syncthreads();
    }
    if (tid < COUT) { atomicAdd(&s1g[tid], l1[tid]); atomicAdd(&s2g[tid], l2[tid]); }
}

// --- K5: batchnorm (training stats) + elu ---
template <int COUT>
__global__ void k_bn_elu(const float* __restrict__ act, const float* __restrict__ s1g,
                         const float* __restrict__ s2g, const float* __restrict__ gamma,
                         const float* __restrict__ beta, float* __restrict__ out) {
    int t = blockIdx.x * blockDim.x + threadIdx.x;
    if (t >= N_NODES * COUT) return;
    int o = t % COUT;
    float m = s1g[o] * (1.0f / N_NODES);
    float v = s2g[o] * (1.0f / N_NODES) - m * m;
    float x = (act[t] - m) * rsqrtf(v + 1e-5f) * gamma[o] + beta[o];
    out[t] = elu_f(x);
}

// --- K6: fc1 (64->128) + elu + fc2 (128->1) + elu + global sum. 2 nodes per block. ---
__global__ void k_fc_sum(const float* __restrict__ h2, const float* __restrict__ fc1w,
                         const float* __restrict__ fc1b, const float* __restrict__ fc2w,
                         const float* __restrict__ fc2b, float* __restrict__ out) {
    __shared__ float lds[256];
    int tid = threadIdx.x;
    int j = tid & 127;
    int n = blockIdx.x * 2 + (tid >> 7);
    float v = 0.f;
    if (n < N_NODES) {
        float s = fc1b[j];
        const float* hr = h2 + n * C2;
#pragma unroll
        for (int i = 0; i < C2; i++) s += hr[i] * fc1w[i * 128 + j];
        v = elu_f(s) * fc2w[j];
    }
    lds[tid] = v;
    __syncthreads();
    for (int s = 64; s > 0; s >>= 1) {
        if ((tid & 127) < s) lds[tid] += lds[tid + s];
        __syncthreads();
    }
    if ((tid & 127) == 0 && n < N_NODES) atomicAdd(out, elu_f(lds[tid] + fc2b[0]));
}

extern "C" void kernel_launch(void* const* d_in, const int* in_sizes, int n_in,
                              void* d_out, int out_size, void* d_ws, size_t ws_size,
                              hipStream_t stream) {
    const float* x        = (const float*)d_in[0];
    const int*   ei       = (const int*)d_in[1];
    const float* ea       = (const float*)d_in[2];
    const float* nn1_w1   = (const float*)d_in[3];
    const float* nn1_b1   = (const float*)d_in[4];
    const float* nn1_w2   = (const float*)d_in[5];
    const float* nn1_b2   = (const float*)d_in[6];
    const float* c1_root  = (const float*)d_in[7];
    const float* c1_bias  = (const float*)d_in[8];
    const float* bn1_g    = (const float*)d_in[9];
    const float* bn1_b    = (const float*)d_in[10];
    const float* nn2_w1   = (const float*)d_in[11];
    const float* nn2_b1   = (const float*)d_in[12];
    const float* nn2_w2   = (const float*)d_in[13];
    const float* nn2_b2   = (const float*)d_in[14];
    const float* c2_root  = (const float*)d_in[15];
    const float* c2_bias  = (const float*)d_in[16];
    const float* bn2_g    = (const float*)d_in[17];
    const float* bn2_b    = (const float*)d_in[18];
    const float* fc1_w    = (const float*)d_in[19];
    const float* fc1_b    = (const float*)d_in[20];
    const float* fc2_w    = (const float*)d_in[21];
    const float* fc2_b    = (const float*)d_in[22];
    float* out = (float*)d_out;

    char* ws = (char*)d_ws;
    size_t off = 0;
    auto alloc = [&](size_t nfloats) -> float* {
        float* p = (float*)(ws + off);
        off += nfloats * sizeof(float);
        off = (off + 255) & ~(size_t)255;
        return p;
    };
    // zeroed region (deg, agg1, agg2, BN sums) must be contiguous & first
    float* deg    = alloc(N_NODES);
    float* agg1   = alloc((size_t)N_NODES * C1);
    float* agg2   = alloc((size_t)N_NODES * C2);
    float* bn1_s1 = alloc(C1);
    float* bn1_s2 = alloc(C1);
    float* bn2_s1 = alloc(C2);
    float* bn2_s2 = alloc(C2);
    size_t zero_bytes = off;
    float* hr1 = alloc((size_t)N_EDGES * HID);
    float* hr2 = alloc((size_t)N_EDGES * HID);
    float* P1  = alloc((size_t)N_NODES * HID * C1);
    float* P2  = alloc((size_t)N_NODES * HID * C2);
    float* a1  = alloc((size_t)N_NODES * C1);
    float* h1  = alloc((size_t)N_NODES * C1);
    float* a2  = alloc((size_t)N_NODES * C2);
    float* h2  = alloc((size_t)N_NODES * C2);
    (void)ws_size;

    hipMemsetAsync(d_ws, 0, zero_bytes, stream);
    hipMemsetAsync(d_out, 0, sizeof(float), stream);

    // edge hidden layers (both convs) + degrees
    k_edge_hidden<<<(N_EDGES + 255) / 256, 256, 0, stream>>>(ea, ei, nn1_w1, nn1_b1,
                                                             nn2_w1, nn2_b1, hr1, hr2, deg);
    // ---- conv1 ----
    k_precompute_P<FN, C1><<<N_NODES, 256, 0, stream>>>(x, nn1_w2, P1);
    k_edge_msg<FN, C1><<<(N_EDGES * C1) / 256, 256, 0, stream>>>(x, ei, hr1, P1, nn1_b2, agg1);
    k_node_update<FN, C1><<<(N_NODES * C1) / 256, 256, 0, stream>>>(x, c1_root, c1_bias, agg1,
                                                                    deg, a1, bn1_s1, bn1_s2);
    k_bn_elu<C1><<<(N_NODES * C1) / 256, 256, 0, stream>>>(a1, bn1_s1, bn1_s2, bn1_g, bn1_b, h1);
    // ---- conv2 ----
    k_precompute_P<C1, C2><<<N_NODES, 256, 0, stream>>>(h1, nn2_w2, P2);
    k_edge_msg<C1, C2><<<(N_EDGES * C2) / 256, 256, 0, stream>>>(h1, ei, hr2, P2, nn2_b2, agg2);
    k_node_update<C1, C2><<<(N_NODES * C2) / 256, 256, 0, stream>>>(h1, c2_root, c2_bias, agg2,
                                                                    deg, a2, bn2_s1, bn2_s2);
    k_bn_elu<C2><<<(N_NODES * C2) / 256, 256, 0, stream>>>(a2, bn2_s1, bn2_s2, bn2_g, bn2_b, h2);
    // ---- fc + global sum ----
    k_fc_sum<<<(N_NODES + 1) / 2, 256, 0, stream>>>(h2, fc1_w, fc1_b, fc2_w, fc2_b, out);
}

// Round 2
// 380.788 us; speedup vs baseline: 1.4125x; 1.4125x over previous
//
#include <hip/hip_runtime.h>
#include <hip/hip_bf16.h>

#define N_NODES 10000
#define N_EDGES 80000
#define FN 16
#define FE 8
#define HID 25
#define C1 32
#define C2 64
#define NU_BLOCKS 256
#define FC_BLOCKS 640

__device__ __forceinline__ float elu_f(float x) { return x > 0.f ? x : (expf(x) - 1.f); }

// --- K1: per-edge hidden layer for both convs: relu(ea@w1+b1), plus degree count ---
__global__ void k_edge_hidden(const float* __restrict__ ea, const int* __restrict__ ei,
                              const float* __restrict__ w1a, const float* __restrict__ b1a,
                              const float* __restrict__ w1b, const float* __restrict__ b1b,
                              float* __restrict__ hr1, float* __restrict__ hr2,
                              float* __restrict__ deg) {
    __shared__ float sw1a[FE * HID], sw1b[FE * HID], sb1a[HID], sb1b[HID];
    int tid = threadIdx.x;
    for (int i = tid; i < FE * HID; i += blockDim.x) { sw1a[i] = w1a[i]; sw1b[i] = w1b[i]; }
    if (tid < HID) { sb1a[tid] = b1a[tid]; sb1b[tid] = b1b[tid]; }
    __syncthreads();
    int e = blockIdx.x * blockDim.x + tid;
    if (e >= N_EDGES) return;
    float a[FE];
#pragma unroll
    for (int i = 0; i < FE; i++) a[i] = ea[e * FE + i];
#pragma unroll
    for (int k = 0; k < HID; k++) {
        float s1 = sb1a[k], s2 = sb1b[k];
#pragma unroll
        for (int i = 0; i < FE; i++) { s1 += a[i] * sw1a[i * HID + k]; s2 += a[i] * sw1b[i * HID + k]; }
        hr1[e * HID + k] = fmaxf(s1, 0.f);
        hr2[e * HID + k] = fmaxf(s2, 0.f);
    }
    atomicAdd(&deg[ei[N_EDGES + e]], 1.0f);
}

// --- K2: per-node precompute P[n,k,o] = sum_i x[n,i] * w2[k, i*COUT + o] ---
template <int CIN, int COUT>
__global__ void k_precompute_P(const float* __restrict__ xin, const float* __restrict__ w2,
                               float* __restrict__ P) {
    __shared__ float xn[CIN];
    int n = blockIdx.x;
    int tid = threadIdx.x;
    if (tid < CIN) xn[tid] = xin[n * CIN + tid];
    __syncthreads();
    for (int ko = tid; ko < HID * COUT; ko += blockDim.x) {
        int k = ko / COUT, o = ko % COUT;
        float s = 0.f;
#pragma unroll
        for (int i = 0; i < CIN; i++) s += xn[i] * w2[k * (CIN * COUT) + i * COUT + o];
        P[(size_t)n * (HID * COUT) + ko] = s;
    }
}

// --- K3: per-edge message msg[e,o] = sum_k hr[e,k]*P[src,k,o] + sum_i x[src,i]*b2[i,o];
//         atomic scatter into agg[dst,o] (random dst -> low contention) ---
template <int CIN, int COUT>
__global__ void k_edge_msg(const float* __restrict__ xin, const int* __restrict__ ei,
                           const float* __restrict__ hr, const float* __restrict__ P,
                           const float* __restrict__ b2, float* __restrict__ agg) {
    int t = blockIdx.x * blockDim.x + threadIdx.x;
    int e = t / COUT, o = t % COUT;
    if (e >= N_EDGES) return;
    int src = ei[e], dst = ei[N_EDGES + e];
    const float* Pr = P + (size_t)src * (HID * COUT) + o;
    const float* hre = hr + e * HID;
    float s = 0.f;
#pragma unroll
    for (int k = 0; k < HID; k++) s += hre[k] * Pr[k * COUT];
    const float* xr = xin + src * CIN;
#pragma unroll
    for (int i = 0; i < CIN; i++) s += xr[i] * b2[i * COUT + o];
    atomicAdd(&agg[dst * COUT + o], s);
}

// --- K4: node update: act = elu(x@root + agg/max(deg,1) + bias); BN sums via
//         per-thread register accumulation + 1 LDS reduce + 256 atomics/chan ---
template <int CIN, int COUT>
__global__ void k_node_update(const float* __restrict__ xin, const float* __restrict__ root,
                              const float* __restrict__ bias, const float* __restrict__ agg,
                              const float* __restrict__ deg, float* __restrict__ act,
                              float* __restrict__ s1g, float* __restrict__ s2g) {
    __shared__ float l1[256], l2[256];
    int tid = threadIdx.x;
    int o = tid % COUT;  // stride (NU_BLOCKS*256) % COUT == 0 -> channel invariant
    float b = bias[o];
    float rcol[CIN];
#pragma unroll
    for (int i = 0; i < CIN; i++) rcol[i] = root[i * COUT + o];
    float acc1 = 0.f, acc2 = 0.f;
    for (int t = blockIdx.x * 256 + tid; t < N_NODES * COUT; t += NU_BLOCKS * 256) {
        int n = t / COUT;
        float s = b;
        const float* xr = xin + n * CIN;
#pragma unroll
        for (int i = 0; i < CIN; i++) s += xr[i] * rcol[i];
        s += agg[t] / fmaxf(deg[n], 1.0f);
        float a = elu_f(s);
        act[t] = a;
        acc1 += a; acc2 += a * a;
    }
    l1[tid] = acc1; l2[tid] = acc2;
    __syncthreads();
    for (int s = 128; s >= COUT; s >>= 1) {
        if (tid < s) { l1[tid] += l1[tid + s]; l2[tid] += l2[tid + s]; }
        __syncthreads();
    }
    if (tid < COUT) { atomicAdd(&s1g[tid], l1[tid]); atomicAdd(&s2g[tid], l2[tid]); }
}

// --- K5: batchnorm (training stats) + elu ---
template <int COUT>
__global__ void k_bn_elu(const float* __restrict__ act, const float* __restrict__ s1g,
                         const float* __restrict__ s2g, const float* __restrict__ gamma,
                         const float* __restrict__ beta, float* __restrict__ out) {
    int t = blockIdx.x * blockDim.x + threadIdx.x;
    if (t >= N_NODES * COUT) return;
    int o = t % COUT;
    float m = s1g[o] * (1.0f / N_NODES);
    float v = s2g[o] * (1.0f / N_NODES) - m * m;
    float x = (act[t] - m) * rsqrtf(v + 1e-5f) * gamma[o] + beta[o];
    out[t] = elu_f(x);
}

// --- K6: fc1 (64->128) + elu + fc2 (128->1) + elu + per-block partial sums.
//         One node per wave: lane j handles fc1 outputs j and j+64; shuffle reduce. ---
__global__ void k_fc_sum(const float* __restrict__ h2, const float* __restrict__ fc1w,
                         const float* __restrict__ fc1b, const float* __restrict__ fc2w,
                         const float* __restrict__ fc2b, float* __restrict__ partial) {
    int tid = threadIdx.x;
    int lane = tid & 63;
    int wave = tid >> 6;
    float b0 = fc1b[lane], b1 = fc1b[lane + 64];
    float w0 = fc2w[lane], w1 = fc2w[lane + 64];
    float fb = fc2b[0];
    float acc = 0.f;
    for (int n = blockIdx.x * 4 + wave; n < N_NODES; n += FC_BLOCKS * 4) {
        const float* hr = h2 + n * C2;
        float s0 = b0, s1 = b1;
#pragma unroll
        for (int i = 0; i < C2; i++) {
            float hv = hr[i];  // broadcast within wave
            s0 += hv * fc1w[i * 128 + lane];
            s1 += hv * fc1w[i * 128 + 64 + lane];
        }
        float v = elu_f(s0) * w0 + elu_f(s1) * w1;
#pragma unroll
        for (int off = 32; off > 0; off >>= 1) v += __shfl_down(v, off);
        if (lane == 0) acc += elu_f(v + fb);
    }
    __shared__ float lds[4];
    if (lane == 0) lds[wave] = acc;
    __syncthreads();
    if (tid == 0) partial[blockIdx.x] = lds[0] + lds[1] + lds[2] + lds[3];
}

// --- K7: final reduction of FC_BLOCKS partials -> out[0] ---
__global__ void k_fc_reduce(const float* __restrict__ partial, float* __restrict__ out) {
    __shared__ float lds[256];
    int tid = threadIdx.x;
    float s = 0.f;
    for (int i = tid; i < FC_BLOCKS; i += 256) s += partial[i];
    lds[tid] = s;
    __syncthreads();
    for (int k = 128; k > 0; k >>= 1) {
        if (tid < k) lds[tid] += lds[tid + k];
        __syncthreads();
    }
    if (tid == 0) out[0] = lds[0];
}

extern "C" void kernel_launch(void* const* d_in, const int* in_sizes, int n_in,
                              void* d_out, int out_size, void* d_ws, size_t ws_size,
                              hipStream_t stream) {
    const float* x        = (const float*)d_in[0];
    const int*   ei       = (const int*)d_in[1];
    const float* ea       = (const float*)d_in[2];
    const float* nn1_w1   = (const float*)d_in[3];
    const float* nn1_b1   = (const float*)d_in[4];
    const float* nn1_w2   = (const float*)d_in[5];
    const float* nn1_b2   = (const float*)d_in[6];
    const float* c1_root  = (const float*)d_in[7];
    const float* c1_bias  = (const float*)d_in[8];
    const float* bn1_g    = (const float*)d_in[9];
    const float* bn1_b    = (const float*)d_in[10];
    const float* nn2_w1   = (const float*)d_in[11];
    const float* nn2_b1   = (const float*)d_in[12];
    const float* nn2_w2   = (const float*)d_in[13];
    const float* nn2_b2   = (const float*)d_in[14];
    const float* c2_root  = (const float*)d_in[15];
    const float* c2_bias  = (const float*)d_in[16];
    const float* bn2_g    = (const float*)d_in[17];
    const float* bn2_b    = (const float*)d_in[18];
    const float* fc1_w    = (const float*)d_in[19];
    const float* fc1_b    = (const float*)d_in[20];
    const float* fc2_w    = (const float*)d_in[21];
    const float* fc2_b    = (const float*)d_in[22];
    float* out = (float*)d_out;

    char* ws = (char*)d_ws;
    size_t off = 0;
    auto alloc = [&](size_t nfloats) -> float* {
        float* p = (float*)(ws + off);
        off += nfloats * sizeof(float);
        off = (off + 255) & ~(size_t)255;
        return p;
    };
    // zeroed region (deg, agg1, agg2, BN sums) must be contiguous & first
    float* deg    = alloc(N_NODES);
    float* agg1   = alloc((size_t)N_NODES * C1);
    float* agg2   = alloc((size_t)N_NODES * C2);
    float* bn1_s1 = alloc(C1);
    float* bn1_s2 = alloc(C1);
    float* bn2_s1 = alloc(C2);
    float* bn2_s2 = alloc(C2);
    size_t zero_bytes = off;
    float* hr1 = alloc((size_t)N_EDGES * HID);
    float* hr2 = alloc((size_t)N_EDGES * HID);
    float* P1  = alloc((size_t)N_NODES * HID * C1);
    float* P2  = alloc((size_t)N_NODES * HID * C2);
    float* a1  = alloc((size_t)N_NODES * C1);
    float* h1  = alloc((size_t)N_NODES * C1);
    float* a2  = alloc((size_t)N_NODES * C2);
    float* h2  = alloc((size_t)N_NODES * C2);
    float* partial = alloc(FC_BLOCKS);
    (void)ws_size;

    hipMemsetAsync(d_ws, 0, zero_bytes, stream);

    // edge hidden layers (both convs) + degrees
    k_edge_hidden<<<(N_EDGES + 255) / 256, 256, 0, stream>>>(ea, ei, nn1_w1, nn1_b1,
                                                             nn2_w1, nn2_b1, hr1, hr2, deg);
    // ---- conv1 ----
    k_precompute_P<FN, C1><<<N_NODES, 256, 0, stream>>>(x, nn1_w2, P1);
    k_edge_msg<FN, C1><<<(N_EDGES * C1) / 256, 256, 0, stream>>>(x, ei, hr1, P1, nn1_b2, agg1);
    k_node_update<FN, C1><<<NU_BLOCKS, 256, 0, stream>>>(x, c1_root, c1_bias, agg1,
                                                         deg, a1, bn1_s1, bn1_s2);
    k_bn_elu<C1><<<(N_NODES * C1) / 256, 256, 0, stream>>>(a1, bn1_s1, bn1_s2, bn1_g, bn1_b, h1);
    // ---- conv2 ----
    k_precompute_P<C1, C2><<<N_NODES, 256, 0, stream>>>(h1, nn2_w2, P2);
    k_edge_msg<C1, C2><<<(N_EDGES * C2) / 256, 256, 0, stream>>>(h1, ei, hr2, P2, nn2_b2, agg2);
    k_node_update<C1, C2><<<NU_BLOCKS, 256, 0, stream>>>(h1, c2_root, c2_bias, agg2,
                                                         deg, a2, bn2_s1, bn2_s2);
    k_bn_elu<C2><<<(N_NODES * C2) / 256, 256, 0, stream>>>(a2, bn2_s1, bn2_s2, bn2_g, bn2_b, h2);
    // ---- fc + global sum ----
    k_fc_sum<<<FC_BLOCKS, 256, 0, stream>>>(h2, fc1_w, fc1_b, fc2_w, fc2_b, partial);
    k_fc_reduce<<<1, 256, 0, stream>>>(partial, out);
}